// Round 4
// baseline (380.049 us; speedup 1.0000x reference)
//
#include <hip/hip_runtime.h>
#include <math.h>

#define IMG_H 512
#define IMG_W 512
#define CH    3
#define BX    16                 // tile width  (threads x)
#define TY    16                 // threads y
#define PPT   2                  // pixels per thread (vertical)
#define TILE_H (TY * PPT)        // 32
#define PAD   2
#define TPW   (BX + 2 * PAD)     // 20
#define TPH   (TILE_H + 2 * PAD) // 36

typedef float v2f __attribute__((ext_vector_type(2)));

#if __has_builtin(__builtin_amdgcn_exp2f)
#define EXP2(x) __builtin_amdgcn_exp2f(x)
#else
#define EXP2(x) exp2f(x)
#endif

#if __has_builtin(__builtin_amdgcn_rcpf)
#define RCP(x) __builtin_amdgcn_rcpf(x)
#else
#define RCP(x) (1.0f / (x))
#endif

__device__ __forceinline__ int reflect_idx(int i, int n) {
    i = (i < 0) ? -i : i;
    i = (i >= n) ? (2 * n - 2 - i) : i;
    return i;
}

__global__ __launch_bounds__(256, 6)
void bilateral_kernel(const float* __restrict__ in, float* __restrict__ out) {
    // Entry: {r*S, g*S, b*S, -||s*S||^2}, S^2 = 312.5 * log2(e).
    // Read pattern (lanes 2 rows apart = 160 dwords = 0 mod 32) measured
    // conflict-free in R3 (SQ_LDS_BANK_CONFLICT = 0).
    __shared__ float4 lds[TPH][TPW];

    const float S = sqrtf(312.5f * 1.44269504088896f);  // compile-time folded

    const int b  = blockIdx.z;
    const int by = blockIdx.y * TILE_H;
    const int bx = blockIdx.x * BX;
    const int tx = threadIdx.x;
    const int ty = threadIdx.y;
    const int tid = ty * BX + tx;

    // Cooperative halo staging with reflect padding (36x20 = 720 entries).
    for (int i = tid; i < TPH * TPW; i += 256) {
        const int py = i / TPW;
        const int px = i - py * TPW;
        const int gy = reflect_idx(by + py - PAD, IMG_H);
        const int gx = reflect_idx(bx + px - PAD, IMG_W);
        const float* src = in + ((size_t)(b * IMG_H + gy) * IMG_W + gx) * CH;
        const float s0 = src[0] * S;
        const float s1 = src[1] * S;
        const float s2 = src[2] * S;
        const float mq = -fmaf(s0, s0, fmaf(s1, s1, s2 * s2));
        lds[py][px] = make_float4(s0, s1, s2, mq);
    }
    __syncthreads();

    // log2 of normalized 1-D gaussian weights, index min(d, 4-d).
    const float CW[3] = { -4.1978935f, -2.0338538f, -1.3125121f };

    const int ty2 = ty * PPT;

    // Per-center constants (center rows by+ty2+j, col bx+tx).
    v2f   c01[PPT];    // [2*c.x, 2*c.y]
    v2f   c2z1[PPT];   // [2*c.z, 1.0]
    float cw[PPT];     // c.w = -||c||^2 (scaled)
    #pragma unroll
    for (int j = 0; j < PPT; ++j) {
        const float4 c = lds[ty2 + j + PAD][tx + PAD];
        c01[j]  = (v2f){ c.x + c.x, c.y + c.y };
        c2z1[j] = (v2f){ c.z + c.z, 1.0f };
        cw[j]   = c.w;
    }

    v2f   nxy[PPT];
    float n2[PPT], den[PPT];
    #pragma unroll
    for (int j = 0; j < PPT; ++j) {
        nxy[j] = (v2f){ 0.0f, 0.0f };
        n2[j] = 0.0f; den[j] = 0.0f;
    }

    // Rolling window: 6 tap-rows serve the 2 centers (center j uses rows j..j+4).
    #pragma unroll
    for (int r = 0; r < PPT + 4; ++r) {
        float4 s[5];
        #pragma unroll
        for (int k = 0; k < 5; ++k) {
            s[k] = lds[ty2 + r][tx + k];
            s[k].w += CW[k < 3 ? k : 4 - k];   // fold log2(gv[dx]) into s.w
        }
        #pragma unroll
        for (int j = 0; j < PPT; ++j) {
            const int dy = r - j;
            if (dy < 0 || dy > 4) continue;    // compile-time pruned
            const float base = cw[j] + CW[dy < 3 ? dy : 4 - dy];
            const v2f base0 = (v2f){ base, 0.0f };
            #pragma unroll
            for (int k = 0; k < 5; ++k) {
                const v2f sxy = (v2f){ s[k].x, s[k].y };
                const v2f szw = (v2f){ s[k].z, s[k].w };
                // q = [2cz*sz + base, sw'] ; p = [2cx*sx + q.lo, 2cy*sy + sw']
                const v2f q = __builtin_elementwise_fma(szw, c2z1[j], base0);
                const v2f p = __builtin_elementwise_fma(sxy, c01[j], q);
                const float w = EXP2(p.x + p.y);
                nxy[j] = __builtin_elementwise_fma((v2f){ w, w }, sxy, nxy[j]);
                n2[j]  = fmaf(w, s[k].z, n2[j]);
                den[j] += w;
            }
        }
    }

    #pragma unroll
    for (int j = 0; j < PPT; ++j) {
        const float inv = RCP(den[j] * S);
        const int y = by + ty2 + j;
        float* dst = out + ((size_t)(b * IMG_H + y) * IMG_W + (bx + tx)) * CH;
        dst[0] = fminf(fmaxf(nxy[j].x * inv, 0.0f), 1.0f);
        dst[1] = fminf(fmaxf(nxy[j].y * inv, 0.0f), 1.0f);
        dst[2] = fminf(fmaxf(n2[j]  * inv, 0.0f), 1.0f);
    }
}

extern "C" void kernel_launch(void* const* d_in, const int* in_sizes, int n_in,
                              void* d_out, int out_size, void* d_ws, size_t ws_size,
                              hipStream_t stream) {
    const float* in = (const float*)d_in[0];
    float* out = (float*)d_out;
    const int B = in_sizes[0] / (IMG_H * IMG_W * CH);   // 16

    dim3 block(BX, TY, 1);
    dim3 grid(IMG_W / BX, IMG_H / TILE_H, B);           // 32 x 16 x 16
    bilateral_kernel<<<grid, block, 0, stream>>>(in, out);
}

// Round 5
// 46.814 us; speedup vs baseline: 8.1183x; 8.1183x over previous
//
#include <hip/hip_runtime.h>
#include <math.h>

#define IMG_H 512
#define IMG_W 512
#define CH    3
#define BX    16                 // tile width  (threads x)
#define TY    16                 // threads y
#define PPT   2                  // pixels per thread (vertical)
#define TILE_H (TY * PPT)        // 32
#define PAD   2
#define TPW   (BX + 2 * PAD)     // 20
#define TPWP  (TPW + 1)          // 21 float4 row stride: 84 dwords, breaks bank aliasing
#define TPH   (TILE_H + 2 * PAD) // 36

typedef float v2f __attribute__((ext_vector_type(2)));

#if __has_builtin(__builtin_amdgcn_exp2f)
#define EXP2(x) __builtin_amdgcn_exp2f(x)
#else
#define EXP2(x) exp2f(x)
#endif

#if __has_builtin(__builtin_amdgcn_rcpf)
#define RCP(x) __builtin_amdgcn_rcpf(x)
#else
#define RCP(x) (1.0f / (x))
#endif

__device__ __forceinline__ int reflect_idx(int i, int n) {
    i = (i < 0) ? -i : i;
    i = (i >= n) ? (2 * n - 2 - i) : i;
    return i;
}

__global__ __launch_bounds__(256)
void bilateral_kernel(const float* __restrict__ in, float* __restrict__ out) {
    // Entry: {r*S, g*S, b*S, -||s*S||^2}, S^2 = 312.5 * log2(e).
    __shared__ float4 lds[TPH][TPWP];

    const float S = sqrtf(312.5f * 1.44269504088896f);  // compile-time folded

    const int b  = blockIdx.z;
    const int by = blockIdx.y * TILE_H;
    const int bx = blockIdx.x * BX;
    const int tx = threadIdx.x;
    const int ty = threadIdx.y;
    const int tid = ty * BX + tx;

    // Cooperative halo staging with reflect padding (36x20 = 720 entries).
    for (int i = tid; i < TPH * TPW; i += 256) {
        const int py = i / TPW;
        const int px = i - py * TPW;
        const int gy = reflect_idx(by + py - PAD, IMG_H);
        const int gx = reflect_idx(bx + px - PAD, IMG_W);
        const float* src = in + ((size_t)(b * IMG_H + gy) * IMG_W + gx) * CH;
        const float s0 = src[0] * S;
        const float s1 = src[1] * S;
        const float s2 = src[2] * S;
        const float mq = -fmaf(s0, s0, fmaf(s1, s1, s2 * s2));
        lds[py][px] = make_float4(s0, s1, s2, mq);
    }
    __syncthreads();

    // log2 of normalized 1-D gaussian weights, index min(d, 4-d).
    const float CW[3] = { -4.1978935f, -2.0338538f, -1.3125121f };

    const int ty2 = ty * PPT;

    // Per-center constants (center rows by+ty2+j, col bx+tx).
    v2f   c01[PPT];    // [2*c.x, 2*c.y]
    v2f   c2z1[PPT];   // [2*c.z, 1.0]
    float cw[PPT];     // c.w = -||c||^2 (scaled)
    #pragma unroll
    for (int j = 0; j < PPT; ++j) {
        const float4 c = lds[ty2 + j + PAD][tx + PAD];
        c01[j]  = (v2f){ c.x + c.x, c.y + c.y };
        c2z1[j] = (v2f){ c.z + c.z, 1.0f };
        cw[j]   = c.w;
    }

    v2f   nxy[PPT];
    float n2[PPT], den[PPT];
    #pragma unroll
    for (int j = 0; j < PPT; ++j) {
        nxy[j] = (v2f){ 0.0f, 0.0f };
        n2[j] = 0.0f; den[j] = 0.0f;
    }

    // Rolling window: 6 tap-rows serve the 2 centers (center j uses rows j..j+4).
    #pragma unroll
    for (int r = 0; r < PPT + 4; ++r) {
        float4 s[5];
        #pragma unroll
        for (int k = 0; k < 5; ++k) {
            s[k] = lds[ty2 + r][tx + k];
            s[k].w += CW[k < 3 ? k : 4 - k];   // fold log2(gv[dx]) into s.w
        }
        #pragma unroll
        for (int j = 0; j < PPT; ++j) {
            const int dy = r - j;
            if (dy < 0 || dy > 4) continue;    // compile-time pruned
            const float base = cw[j] + CW[dy < 3 ? dy : 4 - dy];
            const v2f base0 = (v2f){ base, 0.0f };
            #pragma unroll
            for (int k = 0; k < 5; ++k) {
                const v2f sxy = (v2f){ s[k].x, s[k].y };
                const v2f szw = (v2f){ s[k].z, s[k].w };
                // q = [2cz*sz + base, sw'] ; p = [2cx*sx + q.lo, 2cy*sy + sw']
                const v2f q = __builtin_elementwise_fma(szw, c2z1[j], base0);
                const v2f p = __builtin_elementwise_fma(sxy, c01[j], q);
                const float w = EXP2(p.x + p.y);
                nxy[j] = __builtin_elementwise_fma((v2f){ w, w }, sxy, nxy[j]);
                n2[j]  = fmaf(w, s[k].z, n2[j]);
                den[j] += w;
            }
        }
    }

    #pragma unroll
    for (int j = 0; j < PPT; ++j) {
        const float inv = RCP(den[j] * S);
        const int y = by + ty2 + j;
        float* dst = out + ((size_t)(b * IMG_H + y) * IMG_W + (bx + tx)) * CH;
        dst[0] = fminf(fmaxf(nxy[j].x * inv, 0.0f), 1.0f);
        dst[1] = fminf(fmaxf(nxy[j].y * inv, 0.0f), 1.0f);
        dst[2] = fminf(fmaxf(n2[j]  * inv, 0.0f), 1.0f);
    }
}

extern "C" void kernel_launch(void* const* d_in, const int* in_sizes, int n_in,
                              void* d_out, int out_size, void* d_ws, size_t ws_size,
                              hipStream_t stream) {
    const float* in = (const float*)d_in[0];
    float* out = (float*)d_out;
    const int B = in_sizes[0] / (IMG_H * IMG_W * CH);   // 16

    dim3 block(BX, TY, 1);
    dim3 grid(IMG_W / BX, IMG_H / TILE_H, B);           // 32 x 16 x 16
    bilateral_kernel<<<grid, block, 0, stream>>>(in, out);
}

// Round 6
// 42.521 us; speedup vs baseline: 8.9379x; 1.1009x over previous
//
#include <hip/hip_runtime.h>
#include <math.h>

#define IMG_H 512
#define IMG_W 512
#define CH    3
#define TILE  16
#define PAD   2
#define TP    (TILE + 2 * PAD)   // 20

typedef float v2f __attribute__((ext_vector_type(2)));

#if __has_builtin(__builtin_amdgcn_exp2f)
#define EXP2(x) __builtin_amdgcn_exp2f(x)
#else
#define EXP2(x) exp2f(x)
#endif

#if __has_builtin(__builtin_amdgcn_rcpf)
#define RCP(x) __builtin_amdgcn_rcpf(x)
#else
#define RCP(x) (1.0f / (x))
#endif

__device__ __forceinline__ int reflect_idx(int i, int n) {
    i = (i < 0) ? -i : i;
    i = (i >= n) ? (2 * n - 2 - i) : i;
    return i;
}

__global__ __launch_bounds__(256)
void bilateral_kernel(const float* __restrict__ in, float* __restrict__ out) {
    // Entry: {r*S, g*S, b*S, -||s*S||^2}, S^2 = 312.5 * log2(e).
    // Stride 20 float4 (80 dwords). Conflict-free geometry replicated from R3
    // (measured SQ_LDS_BANK_CONFLICT == 0): each wave's four 16-lane groups
    // read rows 4 apart, achieved here via the rp row permutation below.
    __shared__ float4 lds[TP][TP];

    const float S = sqrtf(312.5f * 1.44269504088896f);  // compile-time folded

    const int b  = blockIdx.z;
    const int by = blockIdx.y * TILE;
    const int bx = blockIdx.x * TILE;
    const int tx = threadIdx.x;
    const int ty = threadIdx.y;
    const int tid = ty * TILE + tx;

    // Cooperative halo staging with reflect padding (400 entries, 2 iters).
    for (int i = tid; i < TP * TP; i += 256) {
        const int py = i / TP;
        const int px = i - py * TP;
        const int gy = reflect_idx(by + py - PAD, IMG_H);
        const int gx = reflect_idx(bx + px - PAD, IMG_W);
        const float* src = in + ((size_t)(b * IMG_H + gy) * IMG_W + gx) * CH;
        const float s0 = src[0] * S;
        const float s1 = src[1] * S;
        const float s2 = src[2] * S;
        const float mq = -fmaf(s0, s0, fmaf(s1, s1, s2 * s2));
        ((float4*)lds)[i] = make_float4(s0, s1, s2, mq);
    }
    __syncthreads();

    // Row permutation: wave = 4 consecutive ty values -> rp values 4 apart
    // (e.g. ty 0..3 -> rows 0,4,8,12). Block still covers rows 0..15.
    const int rp = ((ty & 3) << 2) | (ty >> 2);

    // log2 of normalized 1-D gaussian weights, index min(d, 4-d).
    const float CW[3] = { -4.1978935f, -2.0338538f, -1.3125121f };

    const float4 c = lds[rp + PAD][tx + PAD];
    const v2f c01  = (v2f){ c.x + c.x, c.y + c.y };
    const v2f c2z1 = (v2f){ c.z + c.z, 1.0f };
    const float cw0 = c.w + CW[0];
    const float cw1 = c.w + CW[1];
    const float cw2 = c.w + CW[2];
    const float cwd[5] = { cw0, cw1, cw2, cw1, cw0 };   // static-indexed below

    v2f   nxy = (v2f){ 0.0f, 0.0f };
    float n2 = 0.0f, den = 0.0f;

    #pragma unroll
    for (int dy = 0; dy < 5; ++dy) {
        const v2f base0 = (v2f){ cwd[dy], 0.0f };
        #pragma unroll
        for (int k = 0; k < 5; ++k) {
            float4 s = lds[rp + dy][tx + k];
            s.w += CW[k < 3 ? k : 4 - k];   // fold log2(gv[dx]) into s.w
            const v2f sxy = (v2f){ s.x, s.y };
            const v2f szw = (v2f){ s.z, s.w };
            // q = [2cz*sz + (cw + CWdy), s.w'] ; p = [2cx*sx + q.x, 2cy*sy + q.y]
            const v2f q = __builtin_elementwise_fma(szw, c2z1, base0);
            const v2f p = __builtin_elementwise_fma(sxy, c01, q);
            const float w = EXP2(p.x + p.y);
            nxy = __builtin_elementwise_fma((v2f){ w, w }, sxy, nxy);
            n2  = fmaf(w, s.z, n2);
            den += w;
        }
    }

    const float inv = RCP(den * S);
    const int y = by + rp;
    const int x = bx + tx;
    float* dst = out + ((size_t)(b * IMG_H + y) * IMG_W + x) * CH;
    dst[0] = fminf(fmaxf(nxy.x * inv, 0.0f), 1.0f);
    dst[1] = fminf(fmaxf(nxy.y * inv, 0.0f), 1.0f);
    dst[2] = fminf(fmaxf(n2   * inv, 0.0f), 1.0f);
}

extern "C" void kernel_launch(void* const* d_in, const int* in_sizes, int n_in,
                              void* d_out, int out_size, void* d_ws, size_t ws_size,
                              hipStream_t stream) {
    const float* in = (const float*)d_in[0];
    float* out = (float*)d_out;
    const int B = in_sizes[0] / (IMG_H * IMG_W * CH);   // 16

    dim3 block(TILE, TILE, 1);
    dim3 grid(IMG_W / TILE, IMG_H / TILE, B);           // 32 x 32 x 16
    bilateral_kernel<<<grid, block, 0, stream>>>(in, out);
}